// Round 10
// baseline (202.150 us; speedup 1.0000x reference)
//
#include <hip/hip_runtime.h>

typedef short short8 __attribute__((ext_vector_type(8)));
typedef float floatx4 __attribute__((ext_vector_type(4)));
typedef unsigned short u16;
typedef unsigned long long u64;

#define Tn 2048
#define Kdim 1024
// 1/sqrt(64) * log2(e): folded into Q so flash softmax runs in exp2 domain
#define QSCALE 0.18033688011112042f
#define FIXEDMAX 20.0f   // exp2-domain logits are ~+-5; 20 is a safe fixed max

__device__ inline u16 f2bf(float x) {
    union { float f; unsigned u; } c; c.f = x;
    unsigned u = c.u;
    u += 0x7fffu + ((u >> 16) & 1u);   // round-to-nearest-even
    return (u16)(u >> 16);
}
__device__ inline float bf2f(u16 h) {
    union { unsigned u; float f; } c; c.u = ((unsigned)h) << 16;
    return c.f;
}
__device__ inline floatx4 mfma16(short8 a, short8 b, floatx4 c) {
    return __builtin_amdgcn_mfma_f32_16x16x32_bf16(a, b, c, 0, 0, 0);
}
__device__ inline void async16(const void* g, void* l) {
    __builtin_amdgcn_global_load_lds((const __attribute__((address_space(1))) void*)g,
                                     (__attribute__((address_space(3))) void*)l, 16, 0, 0);
}

// ---------------- fused f32 -> bf16 convert + zeroing (vmean, compacted K/V buffers) ----------------
__global__ __launch_bounds__(256) void cvt_all_k(
    const float* __restrict__ x, const float* __restrict__ wq, const float* __restrict__ wk,
    const float* __restrict__ wv, const float* __restrict__ wo, u16* __restrict__ dst,
    float4* __restrict__ vmz, float4* __restrict__ kvz)
{
    int bx = blockIdx.x;
    if (bx >= 8192) {
        int e = bx - 8192;
        float4 z = {0.f, 0.f, 0.f, 0.f};
        if (e == 0) {   // vmean: 2048 floats = 512 float4
            vmz[threadIdx.x] = z;
            vmz[threadIdx.x + 256] = z;
        } else {        // compacted K (8MB) + compacted V (8MB), contiguous: 1M float4
            kvz[(e - 1) * 256 + threadIdx.x] = z;
        }
        return;
    }
    int i = bx * 256 + threadIdx.x;   // float4 index
    const float* s; int off;
    if (i < 1048576) { s = x; off = i; }
    else {
        int j = i - 1048576; int seg = j >> 18; off = j & 262143;
        s = (seg == 0) ? wq : (seg == 1) ? wk : (seg == 2) ? wv : wo;
    }
    float4 v = ((const float4*)s)[off];
    u64 pk = (u64)f2bf(v.x) | ((u64)f2bf(v.y) << 16) | ((u64)f2bf(v.z) << 32) | ((u64)f2bf(v.w) << 48);
    ((u64*)dst)[i] = pk;
}

// ---------------- mask compaction: prefQ[b][t] = #visible keys (mask==0) in [0..t] ----------------
__global__ __launch_bounds__(1024) void compact_k(const int* __restrict__ masks, int* __restrict__ prefQ) {
    int b = blockIdx.x, t = threadIdx.x;
    __shared__ int tmp[1024];
    int v0 = (masks[b * Tn + 2 * t] == 0);
    int v1 = (masks[b * Tn + 2 * t + 1] == 0);
    tmp[t] = v0 + v1;
    __syncthreads();
    for (int off = 1; off < 1024; off <<= 1) {
        int v = (t >= off) ? tmp[t - off] : 0;
        __syncthreads();
        tmp[t] += v;
        __syncthreads();
    }
    int incl = tmp[t];
    prefQ[b * Tn + 2 * t] = incl - v1;
    prefQ[b * Tn + 2 * t + 1] = incl;
}

// ---------------- QKV GEMM: C = A(M,K) @ W(N,K)^T + bias, 128M x 128N tile, BK=64 ----------------
// m97 wave geometry (2x2 wave quadrants, acc[4][4]: 32 MFMA / 16 ds_read per wave-k-step,
// 2x the MFMA:LDS ratio of the 128x64 tile) + XCD-aware 1D grid (768 blocks: xcd=bid&7,
// per XCD 4 n-blocks x 8 m-blocks x 3 z -> per-k-step slice ~320KB, L2-resident; this is
// the fix for R7's 70MB cross-XCD A-refetch). LDS 32KB single-buffered, 2 barriers/k-step.
// z==1 (K) stores rows COMPACTED (visible keys only); z==2 (V) stores transposed with
// COMPACTED columns + vmean column sums over ALL rows (degenerate-row path).
__global__ __launch_bounds__(256) void gemm_qkv_k(
    const u16* __restrict__ A,
    const u16* __restrict__ W0, const u16* __restrict__ W1, const u16* __restrict__ W2,
    const float* __restrict__ b0, const float* __restrict__ b1, const float* __restrict__ b2,
    u16* o0, u16* o1, u16* o2,
    const float2* __restrict__ rope, float* __restrict__ vmean,
    const int* __restrict__ masks, const int* __restrict__ prefQ)
{
    int bid = blockIdx.x;
    int xcd = bid & 7, bi = bid >> 3;        // bi in 0..95
    int z = bi >> 5;                          // 0..2
    int r5 = bi & 31;
    int bx = (xcd & 1) * 4 + (r5 & 3);        // 0..7   (n-block)
    int by = (xcd >> 1) * 8 + (r5 >> 2);      // 0..31  (m-block)

    const u16* W = (z == 0) ? W0 : (z == 1 ? W1 : W2);
    const float* bias = (z == 0) ? b0 : (z == 1 ? b1 : b2);

    __shared__ __align__(16) char lds[32768];   // A [0,16K): 128 rows x 128B; W [16K,32K): 128 rows x 128B
    int tid = threadIdx.x;
    int w = tid >> 6, lane = tid & 63, quad = lane >> 4, l15 = lane & 15;
    int m0 = by * 128, n0 = bx * 128;
    int wm = (w >> 1) * 64, wn = (w & 1) * 64;

    floatx4 acc[4][4];
    floatx4 vzero = {0.f, 0.f, 0.f, 0.f};
#pragma unroll
    for (int i = 0; i < 4; ++i)
#pragma unroll
        for (int j = 0; j < 4; ++j) acc[i][j] = vzero;

    for (int k0 = 0; k0 < Kdim; k0 += 64) {
#pragma unroll
        for (int j = 0; j < 4; ++j) {
            int f = j * 256 + tid, r = f >> 3, c = (f & 7) ^ (r & 7);
            async16(A + (size_t)(m0 + r) * Kdim + k0 + c * 8, lds + j * 4096 + w * 1024);
            async16(W + (size_t)(n0 + r) * Kdim + k0 + c * 8, lds + 16384 + j * 4096 + w * 1024);
        }
        __syncthreads();
        short8 af[4][2];
#pragma unroll
        for (int mt = 0; mt < 4; ++mt) {
            int ra = wm + mt * 16 + l15;
            const char* pa = lds + ra * 128;
#pragma unroll
            for (int ks = 0; ks < 2; ++ks)
                af[mt][ks] = *(const short8*)(pa + (((ks * 4 + quad) ^ (ra & 7)) << 4));
        }
#pragma unroll
        for (int ks = 0; ks < 2; ++ks)
#pragma unroll
            for (int nt = 0; nt < 4; ++nt) {
                int rb = wn + nt * 16 + l15;
                short8 bf = *(const short8*)(lds + 16384 + rb * 128 + (((ks * 4 + quad) ^ (rb & 7)) << 4));
#pragma unroll
                for (int mt = 0; mt < 4; ++mt)
                    acc[mt][nt] = mfma16(af[mt][ks], bf, acc[mt][nt]);
            }
        __syncthreads();
    }

    int mbase = m0 + wm;
    if (z <= 1) {
        float osc = (z == 0) ? QSCALE : 1.0f;
#pragma unroll
        for (int nt = 0; nt < 4; ++nt) {
            int col = n0 + wn + nt * 16 + l15;
            float bv = bias[col];
            int p = (col & 63) >> 1;
#pragma unroll
            for (int mt = 0; mt < 4; ++mt) {
                floatx4 a = acc[mt][nt];
                int row0 = mbase + mt * 16 + quad * 4;
                int bb2 = row0 >> 11, tt0 = row0 & (Tn - 1);
                int mka[4] = {0, 0, 0, 0}, pqa[4] = {0, 0, 0, 0};
                if (z == 1) {
                    int4 mk = *(const int4*)(masks + bb2 * Tn + tt0);
                    int4 pq = *(const int4*)(prefQ + bb2 * Tn + tt0);
                    mka[0] = mk.x; mka[1] = mk.y; mka[2] = mk.z; mka[3] = mk.w;
                    pqa[0] = pq.x; pqa[1] = pq.y; pqa[2] = pq.z; pqa[3] = pq.w;
                }
#pragma unroll
                for (int r = 0; r < 4; ++r) {
                    int row = row0 + r;
                    float v = a[r] + bv;
                    float ov = __shfl_xor(v, 1, 64);
                    float2 cs = rope[(row & (Tn - 1)) * 32 + p];
                    float res = (cs.x * v + ((lane & 1) ? cs.y * ov : -cs.y * ov)) * osc;
                    float pres = __shfl_xor(res, 1, 64);
                    if (!(lane & 1)) {
                        unsigned pk = (unsigned)f2bf(res) | ((unsigned)f2bf(pres) << 16);
                        if (z == 0) {
                            *(unsigned*)(o0 + (size_t)row * 1024 + col) = pk;
                        } else if (mka[r] == 0) {
                            int rowc = bb2 * Tn + pqa[r] - 1;
                            *(unsigned*)(o1 + (size_t)rowc * 1024 + col) = pk;
                        }
                    }
                }
            }
        }
    } else {
#pragma unroll
        for (int nt = 0; nt < 4; ++nt) {
            int col = n0 + wn + nt * 16 + l15;
            float bv = b2[col];
            float csum = 16.0f * bv;   // this thread's 16 rows of column col (incl bias)
#pragma unroll
            for (int mt = 0; mt < 4; ++mt) {
                floatx4 a = acc[mt][nt];
                int row0 = mbase + mt * 16 + quad * 4;
                int bb2 = row0 >> 11, t0 = row0 & (Tn - 1);
                int4 mk = *(const int4*)(masks + bb2 * Tn + t0);
                int4 pq = *(const int4*)(prefQ + bb2 * Tn + t0);
                int mka[4] = {mk.x, mk.y, mk.z, mk.w};
                int pqa[4] = {pq.x, pq.y, pq.z, pq.w};
#pragma unroll
                for (int i = 0; i < 4; ++i) {
                    if (mka[i] == 0)
                        o2[(size_t)(bb2 * 1024 + col) * Tn + pqa[i] - 1] = f2bf(a[i] + bv);
                }
                csum += a[0] + a[1] + a[2] + a[3];
            }
            // reduce the 4 quads (same col, different row groups); waves 0/2 and 1/3 share cols -> atomic
            csum += __shfl_xor(csum, 16, 64);
            csum += __shfl_xor(csum, 32, 64);
            if (quad == 0) {
                int bb = m0 >> 11;   // batch constant per block
                atomicAdd(&vmean[bb * 1024 + col], csum);
            }
        }
    }
}

// ---------------- O-projection GEMM: out = Y(M,K) @ Wo(N,K)^T, f32 out, 128M x 64N tile ----------------
// XCD-aware 1D grid (512 blocks): xcd = bid&7, each XCD owns an 8x8 (x,y) sub-grid.
__global__ __launch_bounds__(256, 5) void gemm_o_k(
    const u16* __restrict__ A, const u16* __restrict__ W, float* __restrict__ out)
{
    int bid = blockIdx.x;
    int xcd = bid & 7, bi = bid >> 3;        // bi in 0..63
    int bx = (xcd & 1) * 8 + (bi & 7);        // 0..15
    int by = (xcd >> 1) * 8 + (bi >> 3);      // 0..31

    __shared__ __align__(16) char lds[24576];   // A [0,16K): 128 rows x 128B; W [16K,24K): 64 rows x 128B
    int tid = threadIdx.x;
    int w = tid >> 6, lane = tid & 63, quad = lane >> 4, l15 = lane & 15;
    int m0 = by * 128, n0 = bx * 64;
    int wm = w * 32;

    floatx4 acc[2][4];
    floatx4 vzero = {0.f, 0.f, 0.f, 0.f};
#pragma unroll
    for (int i = 0; i < 2; ++i)
#pragma unroll
        for (int j = 0; j < 4; ++j) acc[i][j] = vzero;

    for (int k0 = 0; k0 < Kdim; k0 += 64) {
#pragma unroll
        for (int j = 0; j < 4; ++j) {
            int f = j * 256 + tid, r = f >> 3, c = (f & 7) ^ (r & 7);
            async16(A + (size_t)(m0 + r) * Kdim + k0 + c * 8, lds + j * 4096 + w * 1024);
        }
#pragma unroll
        for (int j = 0; j < 2; ++j) {
            int f = j * 256 + tid, r = f >> 3, c = (f & 7) ^ (r & 7);
            async16(W + (size_t)(n0 + r) * Kdim + k0 + c * 8, lds + 16384 + j * 4096 + w * 1024);
        }
        __syncthreads();
        short8 af[2][2];
#pragma unroll
        for (int mt = 0; mt < 2; ++mt) {
            int ra = wm + mt * 16 + l15;
            const char* pa = lds + ra * 128;
#pragma unroll
            for (int ks = 0; ks < 2; ++ks)
                af[mt][ks] = *(const short8*)(pa + (((ks * 4 + quad) ^ (ra & 7)) << 4));
        }
#pragma unroll
        for (int ks = 0; ks < 2; ++ks)
#pragma unroll
            for (int nt = 0; nt < 4; ++nt) {
                int rb = nt * 16 + l15;
                short8 bf = *(const short8*)(lds + 16384 + rb * 128 + (((ks * 4 + quad) ^ (rb & 7)) << 4));
                acc[0][nt] = mfma16(af[0][ks], bf, acc[0][nt]);
                acc[1][nt] = mfma16(af[1][ks], bf, acc[1][nt]);
            }
        __syncthreads();
    }

#pragma unroll
    for (int nt = 0; nt < 4; ++nt) {
        int col = n0 + nt * 16 + l15;
#pragma unroll
        for (int mt = 0; mt < 2; ++mt) {
            floatx4 a = acc[mt][nt];
#pragma unroll
            for (int r = 0; r < 4; ++r) {
                int row = m0 + wm + mt * 16 + quad * 4 + r;
                out[(size_t)row * 1024 + col] = a[r];
            }
        }
    }
}

// ---------------- Flash attention over COMPACTED keys ----------------
// Masked keys are dropped entirely (their softmax weight is exactly 0); causality on the
// compacted axis collapses to j < prefQ[q] (compaction preserves key order), folded into
// the MFMA C-init. ~half the tiles of the uncompacted kernel. 1024 blocks, 4/CU at 40KB;
// balanced idx->qt permutation; XCD-clustered bh (4 heads/XCD).
__global__ __launch_bounds__(256) void flash_k(
    const u16* __restrict__ Qb, const u16* __restrict__ Kc, const u16* __restrict__ Vtc,
    const int* __restrict__ prefQ, const float* __restrict__ vmean, u16* __restrict__ Yb)
{
    int bid = blockIdx.x;
    int bh = (bid & 7) * 4 + ((bid >> 3) & 3);
    int idx = bid >> 5;                 // 0..31
    int pg = idx >> 3, pr = idx & 7;
    int qt = (pg == 0) ? 31 - pr : (pg == 1) ? pr : (pg == 2) ? 23 - pr : 8 + pr;
    int b = bh >> 4, h = bh & 15;
    int tid = threadIdx.x, w = tid >> 6, lane = tid & 63, quad = lane >> 4, l15 = lane & 15;
    int sc = (lane & 7) ^ (lane >> 3);   // staging chunk so that LDS slot = chunk ^ (row&7)

    __shared__ __align__(16) u16 ldsK[2][64 * 64];   // row=key, 8x16B slots, swizzled (16KB)
    __shared__ __align__(16) u16 ldsV[2][64 * 64];   // row=d,   8x16B slots, swizzled (16KB)
    __shared__ __align__(16) u16 ldsP[4][16 * 64];   // per wave, 16 rows x 128B, swizzled (8KB)

    int ktiles = (prefQ[b * Tn + qt * 64 + 63] + 63) >> 6;   // visible keys for last row of tile

    auto stage = [&](int bb, int k0) {
#pragma unroll
        for (int j = 0; j < 2; ++j) {
            int row = j * 32 + w * 8 + (lane >> 3);
            const u16* gk = Kc + (size_t)(b * Tn + k0 + row) * 1024 + h * 64 + sc * 8;
            async16(gk, (char*)&ldsK[bb][0] + (j * 32 + w * 8) * 128);
            const u16* gv = Vtc + (size_t)(b * 1024 + h * 64 + row) * Tn + k0 + sc * 8;
            async16(gv, (char*)&ldsV[bb][0] + (j * 32 + w * 8) * 128);
        }
    };
    floatx4 vzero = {0.f, 0.f, 0.f, 0.f};

    int q0 = qt * 64 + w * 16;
    int pq[4];
#pragma unroll
    for (int r = 0; r < 4; ++r) pq[r] = prefQ[b * Tn + q0 + quad * 4 + r];   // visible-count per query

    short8 qf[2];
    {
        const u16* qp = Qb + (size_t)(b * Tn + q0 + l15) * 1024 + h * 64 + quad * 8;
        qf[0] = *(const short8*)qp;
        qf[1] = *(const short8*)(qp + 32);
    }
    floatx4 o[4];
    float lsum[4] = {0.f, 0.f, 0.f, 0.f};
#pragma unroll
    for (int i = 0; i < 4; ++i) o[i] = vzero;

    if (ktiles > 0) stage(0, 0);
    for (int kt = 0; kt < ktiles; ++kt) {
        int k0 = kt * 64;
        int bb = kt & 1;
        __syncthreads();   // tile kt staged; all waves done with other buffer

        short8 kf[4][2], vf[4][2];
#pragma unroll
        for (int f = 0; f < 4; ++f) {
            int key = f * 16 + l15;
            const char* kbase = (const char*)&ldsK[bb][0] + key * 128;
            const char* vbase = (const char*)&ldsV[bb][0] + key * 128;
#pragma unroll
            for (int ks = 0; ks < 2; ++ks) {
                int slot = ((quad + ks * 4) ^ (key & 7)) << 4;
                kf[f][ks] = *(const short8*)(kbase + slot);
                vf[f][ks] = *(const short8*)(vbase + slot);
            }
        }
        if (kt + 1 < ktiles) stage(bb ^ 1, k0 + 64);   // prefetch flies during compute

        // causal+mask+fixed-max folded into MFMA C-init: compacted key j visible iff j < pq[r]
        floatx4 ci[4];
#pragma unroll
        for (int f = 0; f < 4; ++f) {
            int jj = k0 + f * 16 + l15;
#pragma unroll
            for (int r = 0; r < 4; ++r)
                ci[f][r] = (jj < pq[r]) ? -FIXEDMAX : -1e10f;
        }

        floatx4 s[4];
        __builtin_amdgcn_s_setprio(1);
#pragma unroll
        for (int f = 0; f < 4; ++f) {
            s[f] = mfma16(qf[0], kf[f][0], ci[f]);
            s[f] = mfma16(qf[1], kf[f][1], s[f]);
        }
        __builtin_amdgcn_s_setprio(0);

#pragma unroll
        for (int r = 0; r < 4; ++r) {
            float psum = 0.f;
#pragma unroll
            for (int f = 0; f < 4; ++f) {
                float p = __builtin_amdgcn_exp2f(s[f][r]);
                psum += p;
                unsigned u = __float_as_uint(p) + 0x8000u;
                int row = quad * 4 + r, key = f * 16 + l15;
                *((u16*)((char*)&ldsP[w][0] + row * 128 +
                         ((((key >> 3) ^ (row & 7))) << 4) + (key & 7) * 2)) = (u16)(u >> 16);
            }
            lsum[r] += psum;
        }
        __asm__ volatile("s_waitcnt lgkmcnt(0)" ::: "memory");   // wave-local P roundtrip
        short8 pf0 = *(const short8*)((const char*)&ldsP[w][0] + l15 * 128 + ((quad ^ (l15 & 7)) << 4));
        short8 pf1 = *(const short8*)((const char*)&ldsP[w][0] + l15 * 128 + (((quad + 4) ^ (l15 & 7)) << 4));
        __builtin_amdgcn_s_setprio(1);
#pragma unroll
        for (int nb = 0; nb < 4; ++nb) {
            o[nb] = mfma16(pf0, vf[nb][0], o[nb]);
            o[nb] = mfma16(pf1, vf[nb][1], o[nb]);
        }
        __builtin_amdgcn_s_setprio(0);
    }

#pragma unroll
    for (int r = 0; r < 4; ++r) {
        int qq = q0 + quad * 4 + r;
        float l = lsum[r];
#pragma unroll
        for (int off = 1; off < 16; off <<= 1) l += __shfl_xor(l, off, 64);
        bool degen = (l == 0.f);   // no visible keys -> reference attends uniformly to ALL keys
        float linv = 1.0f / l;
#pragma unroll
        for (int nb = 0; nb < 4; ++nb) {
            int d = nb * 16 + l15;
            float val = degen ? vmean[b * 1024 + h * 64 + d] * (1.f / 2048.f) : o[nb][r] * linv;
            float pv = __shfl_xor(val, 1, 64);
            if (!(lane & 1)) {
                unsigned pk = (unsigned)f2bf(val) | ((unsigned)f2bf(pv) << 16);
                *(unsigned*)(Yb + (size_t)(b * Tn + qq) * 1024 + h * 64 + d) = pk;
            }
        }
    }
}

extern "C" void kernel_launch(void* const* d_in, const int* in_sizes, int n_in,
                              void* d_out, int out_size, void* d_ws, size_t ws_size,
                              hipStream_t stream) {
    const float* x  = (const float*)d_in[0];
    const int* masks = (const int*)d_in[1];
    const float* Wq = (const float*)d_in[2];
    const float* bq = (const float*)d_in[3];
    const float* Wk = (const float*)d_in[4];
    const float* bk = (const float*)d_in[5];
    const float* Wv = (const float*)d_in[6];
    const float* bv = (const float*)d_in[7];
    const float* Wo = (const float*)d_in[8];
    const float2* rope = (const float2*)d_in[9];
    float* out = (float*)d_out;

    char* ws = (char*)d_ws;
    u16* xb   = (u16*)(ws);
    u16* Wqb  = (u16*)(ws + (8  << 20));
    u16* Wkb  = (u16*)(ws + (10 << 20));
    u16* Wvb  = (u16*)(ws + (12 << 20));
    u16* Wob  = (u16*)(ws + (14 << 20));
    u16* Qb   = (u16*)(ws + (16 << 20));
    u16* Kb2  = (u16*)(ws + (24 << 20));   // compacted K  (zeroed each iter)
    u16* Vt   = (u16*)(ws + (32 << 20));   // compacted V^T (zeroed each iter)
    u16* Yb   = (u16*)(ws + (40 << 20));
    float* vm = (float*)(ws + (48 << 20));
    int* prefQ = (int*)(ws + (48 << 20) + 32768);

    // fused f32 -> bf16 + zero {vmean, compacted K/V buffers (16MB contiguous)}
    cvt_all_k<<<12289, 256, 0, stream>>>(x, Wq, Wk, Wv, Wo, xb, (float4*)vm, (float4*)Kb2);

    // per-batch visible-key prefix counts
    compact_k<<<2, 1024, 0, stream>>>(masks, prefQ);

    // QKV projection, 128x128 m97-geometry + XCD-aware grid; K/V stored COMPACTED; vmean fused
    gemm_qkv_k<<<768, 256, 0, stream>>>(xb, Wqb, Wkb, Wvb, bq, bk, bv,
                                        Qb, Kb2, Vt, rope, vm, masks, prefQ);

    // flash attention over compacted keys (~half the tiles)
    flash_k<<<1024, 256, 0, stream>>>(Qb, Kb2, Vt, prefQ, vm, Yb);

    // output projection -> f32 d_out, 128x64 tile, XCD-aware grid
    gemm_o_k<<<512, 256, 0, stream>>>(Yb, Wob, out);
}

// Round 11
// 177.665 us; speedup vs baseline: 1.1378x; 1.1378x over previous
//
#include <hip/hip_runtime.h>

typedef short short8 __attribute__((ext_vector_type(8)));
typedef float floatx4 __attribute__((ext_vector_type(4)));
typedef unsigned short u16;
typedef unsigned long long u64;

#define Tn 2048
#define Kdim 1024
// 1/sqrt(64) * log2(e): folded into Q so flash softmax runs in exp2 domain
#define QSCALE 0.18033688011112042f
#define FIXEDMAX 20.0f   // exp2-domain logits are ~+-5; 20 is a safe fixed max

__device__ inline u16 f2bf(float x) {
    union { float f; unsigned u; } c; c.f = x;
    unsigned u = c.u;
    u += 0x7fffu + ((u >> 16) & 1u);   // round-to-nearest-even
    return (u16)(u >> 16);
}
__device__ inline float bf2f(u16 h) {
    union { unsigned u; float f; } c; c.u = ((unsigned)h) << 16;
    return c.f;
}
__device__ inline floatx4 mfma16(short8 a, short8 b, floatx4 c) {
    return __builtin_amdgcn_mfma_f32_16x16x32_bf16(a, b, c, 0, 0, 0);
}
__device__ inline void async16(const void* g, void* l) {
    __builtin_amdgcn_global_load_lds((const __attribute__((address_space(1))) void*)g,
                                     (__attribute__((address_space(3))) void*)l, 16, 0, 0);
}

// ---------------- fused: f32->bf16 convert (x,Wq,Wk,Wv,Wo) + zeroing + mask prefix-scan ----------------
// blocks [0,8192): convert; 8192: zero vmean; [8193,12289): zero compacted K/V (16MB);
// [12289,12291): per-batch inclusive prefix prefQ[b][t] = #visible keys (mask==0) in [0..t].
__global__ __launch_bounds__(256) void cvt_all_k(
    const float* __restrict__ x, const float* __restrict__ wq, const float* __restrict__ wk,
    const float* __restrict__ wv, const float* __restrict__ wo, u16* __restrict__ dst,
    float4* __restrict__ vmz, float4* __restrict__ kvz,
    const int* __restrict__ masks, int* __restrict__ prefQ)
{
    int bx = blockIdx.x;
    int tid = threadIdx.x;
    if (bx >= 8192) {
        int e = bx - 8192;
        if (e >= 4097) {
            // mask compaction for batch b (256 threads x 8 elements)
            int b = e - 4097;
            __shared__ int tmp[256];
            int base = b * Tn + tid * 8;
            int v[8], s = 0;
#pragma unroll
            for (int i = 0; i < 8; ++i) { v[i] = (masks[base + i] == 0); s += v[i]; }
            tmp[tid] = s;
            __syncthreads();
            for (int off = 1; off < 256; off <<= 1) {
                int t = (tid >= off) ? tmp[tid - off] : 0;
                __syncthreads();
                tmp[tid] += t;
                __syncthreads();
            }
            int run = tmp[tid] - s;   // exclusive prefix of this thread's chunk
#pragma unroll
            for (int i = 0; i < 8; ++i) { run += v[i]; prefQ[base + i] = run; }
            return;
        }
        float4 z = {0.f, 0.f, 0.f, 0.f};
        if (e == 0) {   // vmean: 2048 floats = 512 float4
            vmz[tid] = z;
            vmz[tid + 256] = z;
        } else {        // compacted K (8MB) + compacted V (8MB), contiguous: 1M float4
            kvz[(e - 1) * 256 + tid] = z;
        }
        return;
    }
    int i = bx * 256 + tid;   // float4 index
    const float* s; int off;
    if (i < 1048576) { s = x; off = i; }
    else {
        int j = i - 1048576; int seg = j >> 18; off = j & 262143;
        s = (seg == 0) ? wq : (seg == 1) ? wk : (seg == 2) ? wv : wo;
    }
    float4 v = ((const float4*)s)[off];
    u64 pk = (u64)f2bf(v.x) | ((u64)f2bf(v.y) << 16) | ((u64)f2bf(v.z) << 32) | ((u64)f2bf(v.w) << 48);
    ((u64*)dst)[i] = pk;
}

// ---------------- QKV GEMM: C = A(M,K) @ W(N,K)^T + bias, 128M x 64N tile, BK=64 ----------------
// XCD-aware 1D grid (1536 blocks): xcd = bid&7, each XCD owns an 8x8 (x,y) sub-grid x all z.
// z==1 (K) stores rows COMPACTED (visible keys only, row t -> prefQ[t]-1). z==2 (V) stores
// transposed with COMPACTED columns, plus vmean column sums over ALL rows (degenerate path).
__global__ __launch_bounds__(256, 5) void gemm_qkv_k(
    const u16* __restrict__ A,
    const u16* __restrict__ W0, const u16* __restrict__ W1, const u16* __restrict__ W2,
    const float* __restrict__ b0, const float* __restrict__ b1, const float* __restrict__ b2,
    u16* o0, u16* o1, u16* o2,
    const float2* __restrict__ rope, float* __restrict__ vmean,
    const int* __restrict__ masks, const int* __restrict__ prefQ)
{
    int bid = blockIdx.x;
    int xcd = bid & 7, bi = bid >> 3;        // bi in 0..191
    int z = bi >> 6;                          // 0..2
    int r6 = bi & 63;
    int bx = (xcd & 1) * 8 + (r6 & 7);        // 0..15  (n-block)
    int by = (xcd >> 1) * 8 + (r6 >> 3);      // 0..31  (m-block)

    const u16* W = (z == 0) ? W0 : (z == 1 ? W1 : W2);
    const float* bias = (z == 0) ? b0 : (z == 1 ? b1 : b2);

    __shared__ __align__(16) char lds[24576];   // A [0,16K): 128 rows x 128B; W [16K,24K): 64 rows x 128B
    int tid = threadIdx.x;
    int w = tid >> 6, lane = tid & 63, quad = lane >> 4, l15 = lane & 15;
    int m0 = by * 128, n0 = bx * 64;
    int wm = w * 32;

    floatx4 acc[2][4];
    floatx4 vzero = {0.f, 0.f, 0.f, 0.f};
#pragma unroll
    for (int i = 0; i < 2; ++i)
#pragma unroll
        for (int j = 0; j < 4; ++j) acc[i][j] = vzero;

    for (int k0 = 0; k0 < Kdim; k0 += 64) {
#pragma unroll
        for (int j = 0; j < 4; ++j) {
            int f = j * 256 + tid, r = f >> 3, c = (f & 7) ^ (r & 7);
            async16(A + (size_t)(m0 + r) * Kdim + k0 + c * 8, lds + j * 4096 + w * 1024);
        }
#pragma unroll
        for (int j = 0; j < 2; ++j) {
            int f = j * 256 + tid, r = f >> 3, c = (f & 7) ^ (r & 7);
            async16(W + (size_t)(n0 + r) * Kdim + k0 + c * 8, lds + 16384 + j * 4096 + w * 1024);
        }
        __syncthreads();
        short8 af[2][2];
#pragma unroll
        for (int mt = 0; mt < 2; ++mt) {
            int ra = wm + mt * 16 + l15;
            const char* pa = lds + ra * 128;
#pragma unroll
            for (int ks = 0; ks < 2; ++ks)
                af[mt][ks] = *(const short8*)(pa + (((ks * 4 + quad) ^ (ra & 7)) << 4));
        }
#pragma unroll
        for (int ks = 0; ks < 2; ++ks)
#pragma unroll
            for (int nt = 0; nt < 4; ++nt) {
                int rb = nt * 16 + l15;
                short8 bf = *(const short8*)(lds + 16384 + rb * 128 + (((ks * 4 + quad) ^ (rb & 7)) << 4));
                acc[0][nt] = mfma16(af[0][ks], bf, acc[0][nt]);
                acc[1][nt] = mfma16(af[1][ks], bf, acc[1][nt]);
            }
        __syncthreads();
    }

    int mbase = m0 + wm;
    if (z <= 1) {
        float osc = (z == 0) ? QSCALE : 1.0f;
#pragma unroll
        for (int nt = 0; nt < 4; ++nt) {
            int col = n0 + nt * 16 + l15;
            float bv = bias[col];
            int p = (col & 63) >> 1;
#pragma unroll
            for (int mt = 0; mt < 2; ++mt) {
                floatx4 a = acc[mt][nt];
                int row0 = mbase + mt * 16 + quad * 4;
                int bb2 = row0 >> 11, tt0 = row0 & (Tn - 1);
                int mka[4] = {0, 0, 0, 0}, pqa[4] = {0, 0, 0, 0};
                if (z == 1) {
                    int4 mk = *(const int4*)(masks + bb2 * Tn + tt0);
                    int4 pq = *(const int4*)(prefQ + bb2 * Tn + tt0);
                    mka[0] = mk.x; mka[1] = mk.y; mka[2] = mk.z; mka[3] = mk.w;
                    pqa[0] = pq.x; pqa[1] = pq.y; pqa[2] = pq.z; pqa[3] = pq.w;
                }
#pragma unroll
                for (int r = 0; r < 4; ++r) {
                    int row = row0 + r;
                    float v = a[r] + bv;
                    float ov = __shfl_xor(v, 1, 64);
                    float2 cs = rope[(row & (Tn - 1)) * 32 + p];
                    float res = (cs.x * v + ((lane & 1) ? cs.y * ov : -cs.y * ov)) * osc;
                    float pres = __shfl_xor(res, 1, 64);
                    if (!(lane & 1)) {
                        unsigned pk = (unsigned)f2bf(res) | ((unsigned)f2bf(pres) << 16);
                        if (z == 0) {
                            *(unsigned*)(o0 + (size_t)row * 1024 + col) = pk;
                        } else if (mka[r] == 0) {
                            int rowc = bb2 * Tn + pqa[r] - 1;
                            *(unsigned*)(o1 + (size_t)rowc * 1024 + col) = pk;
                        }
                    }
                }
            }
        }
    } else {
#pragma unroll
        for (int nt = 0; nt < 4; ++nt) {
            int col = n0 + nt * 16 + l15;
            float bv = b2[col];
            float csum = 8.0f * bv;   // this thread's 8 rows of column col (incl bias)
#pragma unroll
            for (int mt = 0; mt < 2; ++mt) {
                floatx4 a = acc[mt][nt];
                int row0 = mbase + mt * 16 + quad * 4;
                int bb2 = row0 >> 11, t0 = row0 & (Tn - 1);
                int4 mk = *(const int4*)(masks + bb2 * Tn + t0);
                int4 pq = *(const int4*)(prefQ + bb2 * Tn + t0);
                int mka[4] = {mk.x, mk.y, mk.z, mk.w};
                int pqa[4] = {pq.x, pq.y, pq.z, pq.w};
#pragma unroll
                for (int i = 0; i < 4; ++i) {
                    if (mka[i] == 0)
                        o2[(size_t)(bb2 * 1024 + col) * Tn + pqa[i] - 1] = f2bf(a[i] + bv);
                }
                csum += a[0] + a[1] + a[2] + a[3];
            }
            // reduce the 4 quads (same col, different row groups); waves differ -> atomic
            csum += __shfl_xor(csum, 16, 64);
            csum += __shfl_xor(csum, 32, 64);
            if (quad == 0) {
                int bb = m0 >> 11;   // batch constant per block
                atomicAdd(&vmean[bb * 1024 + col], csum);
            }
        }
    }
}

// ---------------- O-projection GEMM: out = Y(M,K) @ Wo(N,K)^T, f32 out, 128M x 64N tile ----------------
// XCD-aware 1D grid (512 blocks): xcd = bid&7, each XCD owns an 8x8 (x,y) sub-grid.
__global__ __launch_bounds__(256, 5) void gemm_o_k(
    const u16* __restrict__ A, const u16* __restrict__ W, float* __restrict__ out)
{
    int bid = blockIdx.x;
    int xcd = bid & 7, bi = bid >> 3;        // bi in 0..63
    int bx = (xcd & 1) * 8 + (bi & 7);        // 0..15
    int by = (xcd >> 1) * 8 + (bi >> 3);      // 0..31

    __shared__ __align__(16) char lds[24576];   // A [0,16K): 128 rows x 128B; W [16K,24K): 64 rows x 128B
    int tid = threadIdx.x;
    int w = tid >> 6, lane = tid & 63, quad = lane >> 4, l15 = lane & 15;
    int m0 = by * 128, n0 = bx * 64;
    int wm = w * 32;

    floatx4 acc[2][4];
    floatx4 vzero = {0.f, 0.f, 0.f, 0.f};
#pragma unroll
    for (int i = 0; i < 2; ++i)
#pragma unroll
        for (int j = 0; j < 4; ++j) acc[i][j] = vzero;

    for (int k0 = 0; k0 < Kdim; k0 += 64) {
#pragma unroll
        for (int j = 0; j < 4; ++j) {
            int f = j * 256 + tid, r = f >> 3, c = (f & 7) ^ (r & 7);
            async16(A + (size_t)(m0 + r) * Kdim + k0 + c * 8, lds + j * 4096 + w * 1024);
        }
#pragma unroll
        for (int j = 0; j < 2; ++j) {
            int f = j * 256 + tid, r = f >> 3, c = (f & 7) ^ (r & 7);
            async16(W + (size_t)(n0 + r) * Kdim + k0 + c * 8, lds + 16384 + j * 4096 + w * 1024);
        }
        __syncthreads();
        short8 af[2][2];
#pragma unroll
        for (int mt = 0; mt < 2; ++mt) {
            int ra = wm + mt * 16 + l15;
            const char* pa = lds + ra * 128;
#pragma unroll
            for (int ks = 0; ks < 2; ++ks)
                af[mt][ks] = *(const short8*)(pa + (((ks * 4 + quad) ^ (ra & 7)) << 4));
        }
#pragma unroll
        for (int ks = 0; ks < 2; ++ks)
#pragma unroll
            for (int nt = 0; nt < 4; ++nt) {
                int rb = nt * 16 + l15;
                short8 bf = *(const short8*)(lds + 16384 + rb * 128 + (((ks * 4 + quad) ^ (rb & 7)) << 4));
                acc[0][nt] = mfma16(af[0][ks], bf, acc[0][nt]);
                acc[1][nt] = mfma16(af[1][ks], bf, acc[1][nt]);
            }
        __syncthreads();
    }

#pragma unroll
    for (int nt = 0; nt < 4; ++nt) {
        int col = n0 + nt * 16 + l15;
#pragma unroll
        for (int mt = 0; mt < 2; ++mt) {
            floatx4 a = acc[mt][nt];
#pragma unroll
            for (int r = 0; r < 4; ++r) {
                int row = m0 + wm + mt * 16 + quad * 4 + r;
                out[(size_t)row * 1024 + col] = a[r];
            }
        }
    }
}

// ---------------- Flash attention over COMPACTED keys ----------------
// Masked keys dropped entirely (their softmax weight is exactly 0); causality on the
// compacted axis collapses to j < prefQ[q], folded into the MFMA C-init. 1024 blocks,
// 4/CU at 40KB; balanced idx->qt permutation (per-CU ktile sums stay r-independent
// after uniform ~halving); XCD-clustered bh (4 heads/XCD).
__global__ __launch_bounds__(256) void flash_k(
    const u16* __restrict__ Qb, const u16* __restrict__ Kc, const u16* __restrict__ Vtc,
    const int* __restrict__ prefQ, const float* __restrict__ vmean, u16* __restrict__ Yb)
{
    int bid = blockIdx.x;
    int bh = (bid & 7) * 4 + ((bid >> 3) & 3);
    int idx = bid >> 5;                 // 0..31
    int pg = idx >> 3, pr = idx & 7;
    int qt = (pg == 0) ? 31 - pr : (pg == 1) ? pr : (pg == 2) ? 23 - pr : 8 + pr;
    int b = bh >> 4, h = bh & 15;
    int tid = threadIdx.x, w = tid >> 6, lane = tid & 63, quad = lane >> 4, l15 = lane & 15;
    int sc = (lane & 7) ^ (lane >> 3);   // staging chunk so that LDS slot = chunk ^ (row&7)

    __shared__ __align__(16) u16 ldsK[2][64 * 64];   // row=key, 8x16B slots, swizzled (16KB)
    __shared__ __align__(16) u16 ldsV[2][64 * 64];   // row=d,   8x16B slots, swizzled (16KB)
    __shared__ __align__(16) u16 ldsP[4][16 * 64];   // per wave, 16 rows x 128B, swizzled (8KB)

    int ktiles = (prefQ[b * Tn + qt * 64 + 63] + 63) >> 6;   // visible keys for last row of tile

    auto stage = [&](int bb, int k0) {
#pragma unroll
        for (int j = 0; j < 2; ++j) {
            int row = j * 32 + w * 8 + (lane >> 3);
            const u16* gk = Kc + (size_t)(b * Tn + k0 + row) * 1024 + h * 64 + sc * 8;
            async16(gk, (char*)&ldsK[bb][0] + (j * 32 + w * 8) * 128);
            const u16* gv = Vtc + (size_t)(b * 1024 + h * 64 + row) * Tn + k0 + sc * 8;
            async16(gv, (char*)&ldsV[bb][0] + (j * 32 + w * 8) * 128);
        }
    };
    floatx4 vzero = {0.f, 0.f, 0.f, 0.f};

    int q0 = qt * 64 + w * 16;
    int pq[4];
#pragma unroll
    for (int r = 0; r < 4; ++r) pq[r] = prefQ[b * Tn + q0 + quad * 4 + r];   // visible-count per query

    short8 qf[2];
    {
        const u16* qp = Qb + (size_t)(b * Tn + q0 + l15) * 1024 + h * 64 + quad * 8;
        qf[0] = *(const short8*)qp;
        qf[1] = *(const short8*)(qp + 32);
    }
    floatx4 o[4];
    float lsum[4] = {0.f, 0.f, 0.f, 0.f};
#pragma unroll
    for (int i = 0; i < 4; ++i) o[i] = vzero;

    if (ktiles > 0) stage(0, 0);
    for (int kt = 0; kt < ktiles; ++kt) {
        int k0 = kt * 64;
        int bb = kt & 1;
        __syncthreads();   // tile kt staged; all waves done with other buffer

        short8 kf[4][2], vf[4][2];
#pragma unroll
        for (int f = 0; f < 4; ++f) {
            int key = f * 16 + l15;
            const char* kbase = (const char*)&ldsK[bb][0] + key * 128;
            const char* vbase = (const char*)&ldsV[bb][0] + key * 128;
#pragma unroll
            for (int ks = 0; ks < 2; ++ks) {
                int slot = ((quad + ks * 4) ^ (key & 7)) << 4;
                kf[f][ks] = *(const short8*)(kbase + slot);
                vf[f][ks] = *(const short8*)(vbase + slot);
            }
        }
        if (kt + 1 < ktiles) stage(bb ^ 1, k0 + 64);   // prefetch flies during compute

        // causal+mask+fixed-max folded into MFMA C-init: compacted key j visible iff j < pq[r]
        floatx4 ci[4];
#pragma unroll
        for (int f = 0; f < 4; ++f) {
            int jj = k0 + f * 16 + l15;
#pragma unroll
            for (int r = 0; r < 4; ++r)
                ci[f][r] = (jj < pq[r]) ? -FIXEDMAX : -1e10f;
        }

        floatx4 s[4];
        __builtin_amdgcn_s_setprio(1);
#pragma unroll
        for (int f = 0; f < 4; ++f) {
            s[f] = mfma16(qf[0], kf[f][0], ci[f]);
            s[f] = mfma16(qf[1], kf[f][1], s[f]);
        }
        __builtin_amdgcn_s_setprio(0);

#pragma unroll
        for (int r = 0; r < 4; ++r) {
            float psum = 0.f;
#pragma unroll
            for (int f = 0; f < 4; ++f) {
                float p = __builtin_amdgcn_exp2f(s[f][r]);
                psum += p;
                unsigned u = __float_as_uint(p) + 0x8000u;
                int row = quad * 4 + r, key = f * 16 + l15;
                *((u16*)((char*)&ldsP[w][0] + row * 128 +
                         ((((key >> 3) ^ (row & 7))) << 4) + (key & 7) * 2)) = (u16)(u >> 16);
            }
            lsum[r] += psum;
        }
        __asm__ volatile("s_waitcnt lgkmcnt(0)" ::: "memory");   // wave-local P roundtrip
        short8 pf0 = *(const short8*)((const char*)&ldsP[w][0] + l15 * 128 + ((quad ^ (l15 & 7)) << 4));
        short8 pf1 = *(const short8*)((const char*)&ldsP[w][0] + l15 * 128 + (((quad + 4) ^ (l15 & 7)) << 4));
        __builtin_amdgcn_s_setprio(1);
#pragma unroll
        for (int nb = 0; nb < 4; ++nb) {
            o[nb] = mfma16(pf0, vf[nb][0], o[nb]);
            o[nb] = mfma16(pf1, vf[nb][1], o[nb]);
        }
        __builtin_amdgcn_s_setprio(0);
    }

#pragma unroll
    for (int r = 0; r < 4; ++r) {
        int qq = q0 + quad * 4 + r;
        float l = lsum[r];
#pragma unroll
        for (int off = 1; off < 16; off <<= 1) l += __shfl_xor(l, off, 64);
        bool degen = (l == 0.f);   // no visible keys -> reference attends uniformly to ALL keys
        float linv = 1.0f / l;
#pragma unroll
        for (int nb = 0; nb < 4; ++nb) {
            int d = nb * 16 + l15;
            float val = degen ? vmean[b * 1024 + h * 64 + d] * (1.f / 2048.f) : o[nb][r] * linv;
            float pv = __shfl_xor(val, 1, 64);
            if (!(lane & 1)) {
                unsigned pk = (unsigned)f2bf(val) | ((unsigned)f2bf(pv) << 16);
                *(unsigned*)(Yb + (size_t)(b * Tn + qq) * 1024 + h * 64 + d) = pk;
            }
        }
    }
}

extern "C" void kernel_launch(void* const* d_in, const int* in_sizes, int n_in,
                              void* d_out, int out_size, void* d_ws, size_t ws_size,
                              hipStream_t stream) {
    const float* x  = (const float*)d_in[0];
    const int* masks = (const int*)d_in[1];
    const float* Wq = (const float*)d_in[2];
    const float* bq = (const float*)d_in[3];
    const float* Wk = (const float*)d_in[4];
    const float* bk = (const float*)d_in[5];
    const float* Wv = (const float*)d_in[6];
    const float* bv = (const float*)d_in[7];
    const float* Wo = (const float*)d_in[8];
    const float2* rope = (const float2*)d_in[9];
    float* out = (float*)d_out;

    char* ws = (char*)d_ws;
    u16* xb   = (u16*)(ws);
    u16* Wqb  = (u16*)(ws + (8  << 20));
    u16* Wkb  = (u16*)(ws + (10 << 20));
    u16* Wvb  = (u16*)(ws + (12 << 20));
    u16* Wob  = (u16*)(ws + (14 << 20));
    u16* Qb   = (u16*)(ws + (16 << 20));
    u16* Kb2  = (u16*)(ws + (24 << 20));   // compacted K  (zeroed each iter)
    u16* Vt   = (u16*)(ws + (32 << 20));   // compacted V^T (zeroed each iter)
    u16* Yb   = (u16*)(ws + (40 << 20));
    float* vm = (float*)(ws + (48 << 20));
    int* prefQ = (int*)(ws + (48 << 20) + 32768);

    // fused f32 -> bf16 + zero {vmean, compacted K/V (16MB)} + mask prefix-scan (launches: 4 total)
    cvt_all_k<<<12291, 256, 0, stream>>>(x, Wq, Wk, Wv, Wo, xb, (float4*)vm, (float4*)Kb2,
                                         masks, prefQ);

    // QKV projection, 128x64 tiles, XCD-aware grid; K/V stored COMPACTED; vmean fused
    gemm_qkv_k<<<1536, 256, 0, stream>>>(xb, Wqb, Wkb, Wvb, bq, bk, bv,
                                         Qb, Kb2, Vt, rope, vm, masks, prefQ);

    // flash attention over compacted keys (~half the tiles)
    flash_k<<<1024, 256, 0, stream>>>(Qb, Kb2, Vt, prefQ, vm, Yb);

    // output projection -> f32 d_out, 128x64 tile, XCD-aware grid
    gemm_o_k<<<512, 256, 0, stream>>>(Yb, Wob, out);
}